// Round 5
// baseline (305.251 us; speedup 1.0000x reference)
//
#include <hip/hip_runtime.h>
#include <math.h>
#include <stdint.h>

typedef unsigned short u16;
typedef __attribute__((ext_vector_type(8))) short short8;
typedef __attribute__((ext_vector_type(4))) float f32x4;
typedef __attribute__((ext_vector_type(16))) float f32x16;

// gate scale: 0.125 (attn scale) * log2(e)  -> p = exp2(s * gate)
#define GATE_SCALE 0.18033688011112042f

#if __has_builtin(__builtin_amdgcn_exp2f)
#define FEXP2(x) __builtin_amdgcn_exp2f(x)
#else
#define FEXP2(x) exp2f(x)
#endif

// fp32 -> bf16 round-to-nearest-even
__device__ __forceinline__ u16 f2b(float f) {
    union { float f; unsigned u; } v; v.f = f;
    unsigned r = v.u + 0x7fffu + ((v.u >> 16) & 1u);
    return (u16)(r >> 16);
}
// fp32 -> bf16 round-half-up
__device__ __forceinline__ u16 f2b_hu(float f) {
    union { float f; unsigned u; } v; v.f = f;
    return (u16)((v.u + 0x8000u) >> 16);
}
__device__ __forceinline__ float b2f(u16 u) {
    union { float f; unsigned u; } v; v.u = ((unsigned)u) << 16; return v.f;
}

// async global->LDS, 16B per lane. lds base wave-uniform; HW adds lane*16.
#define GLL16(gsrc, ldsbase) __builtin_amdgcn_global_load_lds(                    \
    (__attribute__((address_space(1))) void*)(uintptr_t)(gsrc),                   \
    (__attribute__((address_space(3))) void*)(uint32_t)(uintptr_t)(ldsbase),      \
    16, 0, 0)

// ---------------------------------------------------------------------------
// K0a: convert x / w_qkv / w_proj to bf16.
// ---------------------------------------------------------------------------
#define NX4  1572864   // 6291456/4
#define NW14 442368
#define NW24 147456
#define NXW4 (NX4 + NW14 + NW24)   // 2162688

__global__ __launch_bounds__(256) void prep_xw(
    const float4* __restrict__ x, const float4* __restrict__ wq,
    const float4* __restrict__ wp,
    ushort4* __restrict__ xb, ushort4* __restrict__ wqb,
    ushort4* __restrict__ wpb)
{
    size_t i = (size_t)blockIdx.x * 256 + threadIdx.x;
    float4 v; ushort4* dst; size_t j;
    if (i < NX4)            { j = i;               v = x[j];  dst = xb;  }
    else if (i < NX4 + NW14){ j = i - NX4;         v = wq[j]; dst = wqb; }
    else                    { j = i - (NX4 + NW14);v = wp[j]; dst = wpb; }
    ushort4 o; o.x = f2b(v.x); o.y = f2b(v.y); o.z = f2b(v.z); o.w = f2b(v.w);
    dst[j] = o;
}

// ---------------------------------------------------------------------------
// K0b: gate = bf16(GATE_SCALE * sigmoid(mask)) permuted into the 32x32x16
// MFMA C-fragment order used by flash_attn: tile (h, qt[128q], kt[64k]);
// lane (w,l): value idx = ktile*16 + reg maps to
//   q   = qt*128 + 32w + (reg&3) + 8*(reg>>2) + 4*(l>>5)
//   key = kt*64 + ktile*32 + (l&31)
// stored contiguously at tile*8192 + (w*64+l)*32.
// ---------------------------------------------------------------------------
__global__ __launch_bounds__(256) void prep_gate(
    const float* __restrict__ mask, u16* __restrict__ gp)
{
    const int bid = blockIdx.x;                 // (h*8+qt)*16 + kt
    const int kt = bid & 15, qt = (bid >> 4) & 7, h = bid >> 7;
    const int t = threadIdx.x, l = t & 63, w = t >> 6;
    const int ln = l & 31, lh = l >> 5;
    union { u16 u[32]; float4 f[4]; } vals;
    #pragma unroll
    for (int ktile = 0; ktile < 2; ++ktile)
        #pragma unroll
        for (int reg = 0; reg < 16; ++reg) {
            const int q   = qt * 128 + 32 * w + (reg & 3) + 8 * (reg >> 2) + 4 * lh;
            const int key = kt * 64 + ktile * 32 + ln;
            const float m = mask[((size_t)h * 1024 + q) * 1024 + key];
            vals.u[ktile * 16 + reg] = f2b(GATE_SCALE / (1.f + __expf(-m)));
        }
    float4* dst = (float4*)(gp + (size_t)bid * 8192 + (w * 64 + l) * 32);
    #pragma unroll
    for (int s = 0; s < 4; ++s) dst[s] = vals.f[s];
}

// ---------------------------------------------------------------------------
// K1: QKV GEMM, bf16 MFMA 16x16x32, 128x128 tile, BK=32, pipelined dbuf.
// q/k written (B,H,N,64); V written TRANSPOSED (B,H,64,N).
// ---------------------------------------------------------------------------
__global__ __launch_bounds__(256) void qkv_gemm(
    const u16* __restrict__ xb, const u16* __restrict__ wb,
    u16* __restrict__ qb, u16* __restrict__ kb, u16* __restrict__ vb)
{
    __shared__ u16 As[2][4096];
    __shared__ u16 Bs[2][4096];
    const int t = threadIdx.x, l = t & 63, w = t >> 6;
    const int wm = (w & 1) * 64, wn = (w >> 1) * 64;
    const int m0 = blockIdx.y * 128, c0 = blockIdx.x * 128;

    f32x4 acc[4][4];
    #pragma unroll
    for (int i = 0; i < 4; ++i)
        #pragma unroll
        for (int j = 0; j < 4; ++j) { f32x4 z = {0.f,0.f,0.f,0.f}; acc[i][j] = z; }

    const int srow = l >> 2, sseg = l & 3;
    const int gcol = ((sseg ^ (srow & 3)) << 3);
    const u16* a0 = xb + (size_t)(m0 + w * 16 + srow) * 768 + gcol;
    const u16* a1 = a0 + (size_t)64 * 768;
    const u16* b0p = wb + (size_t)(c0 + w * 16 + srow) * 768 + gcol;
    const u16* b1p = b0p + (size_t)64 * 768;
    const int wofs = w * 512;

    const int fr = l & 15, fq = l >> 4;
    const int fseg = (fq ^ (fr & 3)) << 3;

    GLL16(a0, &As[0][wofs]);
    GLL16(a1, &As[0][2048 + wofs]);
    GLL16(b0p, &Bs[0][wofs]);
    GLL16(b1p, &Bs[0][2048 + wofs]);

    for (int kt = 0; kt < 24; ++kt) {
        __syncthreads();
        if (kt < 23) {
            const int kn = (kt + 1) * 32;
            const int nb = (kt + 1) & 1;
            GLL16(a0 + kn, &As[nb][wofs]);
            GLL16(a1 + kn, &As[nb][2048 + wofs]);
            GLL16(b0p + kn, &Bs[nb][wofs]);
            GLL16(b1p + kn, &Bs[nb][2048 + wofs]);
        }
        const u16* A = As[kt & 1];
        const u16* B = Bs[kt & 1];
        short8 af[4], bf[4];
        #pragma unroll
        for (int mt = 0; mt < 4; ++mt)
            af[mt] = *(const short8*)&A[(wm + mt * 16 + fr) * 32 + fseg];
        #pragma unroll
        for (int nt = 0; nt < 4; ++nt)
            bf[nt] = *(const short8*)&B[(wn + nt * 16 + fr) * 32 + fseg];
        #pragma unroll
        for (int mt = 0; mt < 4; ++mt)
            #pragma unroll
            for (int nt = 0; nt < 4; ++nt)
                acc[mt][nt] = __builtin_amdgcn_mfma_f32_16x16x32_bf16(
                    af[mt], bf[nt], acc[mt][nt], 0, 0, 0);
    }

    const int b = m0 >> 10;
    const int n0 = m0 & 1023;
    #pragma unroll
    for (int nt = 0; nt < 4; ++nt) {
        const int c = c0 + wn + nt * 16 + fr;
        const int which = c / 768;
        const int rem = c - which * 768;
        const int h = rem >> 6, d = rem & 63;
        if (which < 2) {
            u16* dst = ((which == 0) ? qb : kb)
                       + ((size_t)(b * 12 + h) * 1024) * 64 + d;
            #pragma unroll
            for (int mt = 0; mt < 4; ++mt)
                #pragma unroll
                for (int r = 0; r < 4; ++r) {
                    const int n = n0 + wm + mt * 16 + fq * 4 + r;
                    dst[(size_t)n * 64] = f2b(acc[mt][nt][r]);
                }
        } else {
            u16* dst = vb + ((size_t)(b * 12 + h) * 64 + d) * 1024
                          + n0 + wm + fq * 4;
            #pragma unroll
            for (int mt = 0; mt < 4; ++mt) {
                ushort4 pk;
                pk.x = f2b(acc[mt][nt][0]); pk.y = f2b(acc[mt][nt][1]);
                pk.z = f2b(acc[mt][nt][2]); pk.w = f2b(acc[mt][nt][3]);
                *(ushort4*)(dst + mt * 16) = pk;
            }
        }
    }
}

// ---------------------------------------------------------------------------
// K2: flash attention on 32x32x16 MFMA (2x MACs per operand byte vs 16x16x32
// -> halves LDS traffic, the measured bottleneck). Block = 128 q-rows; wave
// owns 32 q-rows x all 64 keys of each chunk. Q frags hoisted (kt-invariant).
// Single-buffered K/V (dbuf measured neutral at equal occupancy), 48 KB LDS,
// grid 768 = exactly 3 blocks/CU.
// A/B frag: m(or n)=lane&31, k=(lane>>5)*8+j. C frag: col=lane&31,
// row=(reg&3)+8*(reg>>2)+4*(lane>>5)  [m74/m101-verified].
// ---------------------------------------------------------------------------
__global__ __launch_bounds__(256, 3) void flash_attn(
    const u16* __restrict__ qb, const u16* __restrict__ kb,
    const u16* __restrict__ vt, const u16* __restrict__ gperm,
    u16* __restrict__ aob)
{
    __shared__ u16 Qs[8192];    // 128 x 64
    __shared__ u16 Ks[4096];    // 64 keys x 64 hd
    __shared__ u16 Vts[4096];   // 64 hd  x 64 keys (d-major)
    __shared__ u16 Ps[8192];    // 4 waves x (32 q x 64 keys), wave-private

    const int t = threadIdx.x, l = t & 63, w = t >> 6;
    const int ln = l & 31, lh = l >> 5;
    const int bid = blockIdx.x;                 // (b*12+h)*8 + qt
    const int qt = bid & 7, bh = bid >> 3;      // bh = b*12+h
    const int h = bh % 12, b = bh / 12;
    const int q0 = qt * 128;

    const u16* hq = qb + (size_t)bh * 65536;
    const u16* hk = kb + (size_t)bh * 65536;
    const u16* hv = vt + (size_t)bh * 65536;
    const u16* hg = gperm + ((size_t)(h * 8 + qt) * 16) * 8192 + (w * 64 + l) * 32;

    // staging lane map: 1 GLL16 = 8 rows of 128 B
    const int sr = l >> 3, ss = l & 7;
    const int sg = ((ss ^ (sr & 7)) << 3);      // swizzled global col (elems)

    // stage Q (16 GLL16, 4 per wave) + kt=0 K/V (2+2 per wave)
    #pragma unroll
    for (int jq = 0; jq < 4; ++jq) {
        const int j = w * 4 + jq;
        GLL16(hq + (size_t)(q0 + j * 8 + sr) * 64 + sg, Qs + j * 512);
    }
    {
        const int j0 = w * 2, j1 = w * 2 + 1;
        GLL16(hk + (size_t)(j0 * 8 + sr) * 64 + sg, Ks + j0 * 512);
        GLL16(hk + (size_t)(j1 * 8 + sr) * 64 + sg, Ks + j1 * 512);
        GLL16(hv + (size_t)(j0 * 8 + sr) * 1024 + sg, Vts + j0 * 512);
        GLL16(hv + (size_t)(j1 * 8 + sr) * 1024 + sg, Vts + j1 * 512);
    }
    __syncthreads();

    // hoisted Q A-frags: m = 32w + ln, k = kd*16 + lh*8 + j
    short8 aq[4];
    {
        const int qrow = 32 * w + ln;
        #pragma unroll
        for (int kd = 0; kd < 4; ++kd)
            aq[kd] = *(const short8*)&Qs[qrow * 64 + ((((kd << 1) | lh) ^ (qrow & 7)) << 3)];
    }

    float l_part[16];
    #pragma unroll
    for (int r = 0; r < 16; ++r) l_part[r] = 0.f;
    f32x16 o[2];
    #pragma unroll
    for (int dt = 0; dt < 2; ++dt)
        #pragma unroll
        for (int r = 0; r < 16; ++r) o[dt][r] = 0.f;

    for (int kt = 0; kt < 16; ++kt) {
        // gate for this kt (4x b128 global; overlaps with QK^T mfmas)
        short8 g[4];
        #pragma unroll
        for (int s = 0; s < 4; ++s)
            g[s] = *(const short8*)(hg + (size_t)kt * 8192 + s * 8);

        // S = Q . K^T : two 32x32 key-tiles
        f32x16 sv[2];
        #pragma unroll
        for (int ktile = 0; ktile < 2; ++ktile) {
            f32x16 z;
            #pragma unroll
            for (int r = 0; r < 16; ++r) z[r] = 0.f;
            #pragma unroll
            for (int kd = 0; kd < 4; ++kd) {
                const int krow = ktile * 32 + ln;
                short8 bk = *(const short8*)&Ks[krow * 64 + ((((kd << 1) | lh) ^ (krow & 7)) << 3)];
                z = __builtin_amdgcn_mfma_f32_32x32x16_bf16(aq[kd], bk, z, 0, 0, 0);
            }
            sv[ktile] = z;
        }

        // p = exp2(s * gate); per-lane row sums; P -> wave-private LDS
        #pragma unroll
        for (int ktile = 0; ktile < 2; ++ktile)
            #pragma unroll
            for (int reg = 0; reg < 16; ++reg) {
                const int idx = ktile * 16 + reg;
                const float gv = b2f((u16)g[idx >> 3][idx & 7]);
                const float p = FEXP2(sv[ktile][reg] * gv);
                l_part[reg] += p;
                const int qr = (reg & 3) + 8 * (reg >> 2) + 4 * lh;  // 0..31
                const int col = ktile * 32 + ln;
                Ps[w * 2048 + qr * 64 + (((col >> 3) ^ (qr & 7)) << 3) + (col & 7)]
                    = f2b_hu(p);
            }

        // O += P . V : A = P[m=q][k=key], B = Vt[n=d][k=key]
        short8 ap[4];
        #pragma unroll
        for (int kp = 0; kp < 4; ++kp)
            ap[kp] = *(const short8*)&Ps[w * 2048 + ln * 64 + ((((kp << 1) | lh) ^ (ln & 7)) << 3)];
        #pragma unroll
        for (int dt = 0; dt < 2; ++dt) {
            #pragma unroll
            for (int kp = 0; kp < 4; ++kp) {
                const int drow = dt * 32 + ln;
                short8 bv = *(const short8*)&Vts[drow * 64 + ((((kp << 1) | lh) ^ (drow & 7)) << 3)];
                o[dt] = __builtin_amdgcn_mfma_f32_32x32x16_bf16(ap[kp], bv, o[dt], 0, 0, 0);
            }
        }

        // stage next K/V chunk (single buffer: protect readers, then drain)
        if (kt < 15) {
            __syncthreads();
            const int j0 = w * 2, j1 = w * 2 + 1;
            const size_t ko = (size_t)(kt + 1) * 64;
            GLL16(hk + (ko + j0 * 8 + sr) * 64 + sg, Ks + j0 * 512);
            GLL16(hk + (ko + j1 * 8 + sr) * 64 + sg, Ks + j1 * 512);
            GLL16(hv + (size_t)(j0 * 8 + sr) * 1024 + ko + sg, Vts + j0 * 512);
            GLL16(hv + (size_t)(j1 * 8 + sr) * 1024 + ko + sg, Vts + j1 * 512);
            __syncthreads();
        }
    }

    // deferred l reduction: sum across the 32 lanes sharing lh
    float inv[16];
    #pragma unroll
    for (int reg = 0; reg < 16; ++reg) {
        float s = l_part[reg];
        s += __shfl_xor(s, 1, 32);
        s += __shfl_xor(s, 2, 32);
        s += __shfl_xor(s, 4, 32);
        s += __shfl_xor(s, 8, 32);
        s += __shfl_xor(s, 16, 32);
        inv[reg] = 1.f / s;
    }

    // epilogue -> aob (B,N,768) bf16; col d = dt*32+ln, row q = q0+32w+qr
    #pragma unroll
    for (int reg = 0; reg < 16; ++reg) {
        const int qr = (reg & 3) + 8 * (reg >> 2) + 4 * lh;
        const int n = q0 + 32 * w + qr;
        u16* dst = aob + ((size_t)b * 1024 + n) * 768 + h * 64 + ln;
        dst[0]  = f2b(o[0][reg] * inv[reg]);
        dst[32] = f2b(o[1][reg] * inv[reg]);
    }
}

// ---------------------------------------------------------------------------
// K3: output projection, bf16 MFMA, pipelined, fp32 out + bias.
// ---------------------------------------------------------------------------
__global__ __launch_bounds__(256) void proj_gemm(
    const u16* __restrict__ aob, const u16* __restrict__ wb,
    const float* __restrict__ bproj, float* __restrict__ out)
{
    __shared__ u16 As[2][4096];
    __shared__ u16 Bs[2][4096];
    const int t = threadIdx.x, l = t & 63, w = t >> 6;
    const int wm = (w & 1) * 64, wn = (w >> 1) * 64;
    const int m0 = blockIdx.y * 128, c0 = blockIdx.x * 128;

    f32x4 acc[4][4];
    #pragma unroll
    for (int i = 0; i < 4; ++i)
        #pragma unroll
        for (int j = 0; j < 4; ++j) { f32x4 z = {0.f,0.f,0.f,0.f}; acc[i][j] = z; }

    const int srow = l >> 2, sseg = l & 3;
    const int gcol = ((sseg ^ (srow & 3)) << 3);
    const u16* a0 = aob + (size_t)(m0 + w * 16 + srow) * 768 + gcol;
    const u16* a1 = a0 + (size_t)64 * 768;
    const u16* b0p = wb + (size_t)(c0 + w * 16 + srow) * 768 + gcol;
    const u16* b1p = b0p + (size_t)64 * 768;
    const int wofs = w * 512;

    const int fr = l & 15, fq = l >> 4;
    const int fseg = (fq ^ (fr & 3)) << 3;

    GLL16(a0, &As[0][wofs]);
    GLL16(a1, &As[0][2048 + wofs]);
    GLL16(b0p, &Bs[0][wofs]);
    GLL16(b1p, &Bs[0][2048 + wofs]);

    for (int kt = 0; kt < 24; ++kt) {
        __syncthreads();
        if (kt < 23) {
            const int kn = (kt + 1) * 32;
            const int nb = (kt + 1) & 1;
            GLL16(a0 + kn, &As[nb][wofs]);
            GLL16(a1 + kn, &As[nb][2048 + wofs]);
            GLL16(b0p + kn, &Bs[nb][wofs]);
            GLL16(b1p + kn, &Bs[nb][2048 + wofs]);
        }
        const u16* A = As[kt & 1];
        const u16* B = Bs[kt & 1];
        short8 af[4], bf[4];
        #pragma unroll
        for (int mt = 0; mt < 4; ++mt)
            af[mt] = *(const short8*)&A[(wm + mt * 16 + fr) * 32 + fseg];
        #pragma unroll
        for (int nt = 0; nt < 4; ++nt)
            bf[nt] = *(const short8*)&B[(wn + nt * 16 + fr) * 32 + fseg];
        #pragma unroll
        for (int mt = 0; mt < 4; ++mt)
            #pragma unroll
            for (int nt = 0; nt < 4; ++nt)
                acc[mt][nt] = __builtin_amdgcn_mfma_f32_16x16x32_bf16(
                    af[mt], bf[nt], acc[mt][nt], 0, 0, 0);
    }

    #pragma unroll
    for (int nt = 0; nt < 4; ++nt) {
        const int c = c0 + wn + nt * 16 + fr;
        const float bias = bproj[c];
        #pragma unroll
        for (int mt = 0; mt < 4; ++mt)
            #pragma unroll
            for (int r = 0; r < 4; ++r) {
                const int m = m0 + wm + mt * 16 + fq * 4 + r;
                out[(size_t)m * 768 + c] = acc[mt][nt][r] + bias;
            }
    }
}

// ---------------------------------------------------------------------------
extern "C" void kernel_launch(void* const* d_in, const int* in_sizes, int n_in,
                              void* d_out, int out_size, void* d_ws, size_t ws_size,
                              hipStream_t stream)
{
    const float* x     = (const float*)d_in[0];
    const float* wqkv  = (const float*)d_in[1];
    const float* wproj = (const float*)d_in[2];
    const float* bproj = (const float*)d_in[3];
    const float* mask  = (const float*)d_in[4];
    float* out = (float*)d_out;

    char* ws = (char*)d_ws;
    u16* gperm  = (u16*)(ws);               // 25,165,824 B
    u16* xb     = (u16*)(ws + 25165824);    // 12,582,912 B
    u16* wqkvb  = (u16*)(ws + 37748736);    //  3,538,944 B
    u16* wprojb = (u16*)(ws + 41287680);    //  1,179,648 B
    u16* qb     = (u16*)(ws + 42467328);    // 12,582,912 B
    u16* kb     = (u16*)(ws + 55050240);    // 12,582,912 B
    u16* vb     = (u16*)(ws + 67633152);    // 12,582,912 B (transposed: B,H,64,N)
    u16* aob    = (u16*)(ws + 80216064);    // 12,582,912 B  (total 92.8 MB)

    prep_xw<<<NXW4 / 256, 256, 0, stream>>>(
        (const float4*)x, (const float4*)wqkv, (const float4*)wproj,
        (ushort4*)xb, (ushort4*)wqkvb, (ushort4*)wprojb);

    prep_gate<<<1536, 256, 0, stream>>>(mask, gperm);

    qkv_gemm<<<dim3(18, 64), 256, 0, stream>>>(xb, wqkvb, qb, kb, vb);

    flash_attn<<<768, 256, 0, stream>>>(qb, kb, vb, gperm, aob);

    proj_gemm<<<dim3(6, 64), 256, 0, stream>>>(aob, wprojb, bproj, out);
}

// Round 6
// 243.712 us; speedup vs baseline: 1.2525x; 1.2525x over previous
//
#include <hip/hip_runtime.h>
#include <math.h>
#include <stdint.h>

typedef unsigned short u16;
typedef __attribute__((ext_vector_type(8))) short short8;
typedef __attribute__((ext_vector_type(4))) float f32x4;

// gate scale: 0.125 (attn scale) * log2(e)  -> p = exp2(s * gate)
#define GATE_SCALE 0.18033688011112042f

#if __has_builtin(__builtin_amdgcn_exp2f)
#define FEXP2(x) __builtin_amdgcn_exp2f(x)
#else
#define FEXP2(x) exp2f(x)
#endif

// fp32 -> bf16 round-to-nearest-even
__device__ __forceinline__ u16 f2b(float f) {
    union { float f; unsigned u; } v; v.f = f;
    unsigned r = v.u + 0x7fffu + ((v.u >> 16) & 1u);
    return (u16)(r >> 16);
}
// fp32 -> bf16 round-half-up
__device__ __forceinline__ u16 f2b_hu(float f) {
    union { float f; unsigned u; } v; v.f = f;
    return (u16)((v.u + 0x8000u) >> 16);
}
__device__ __forceinline__ float b2f(u16 u) {
    union { float f; unsigned u; } v; v.u = ((unsigned)u) << 16; return v.f;
}

// async global->LDS, 16B per lane. lds base wave-uniform; HW adds lane*16.
#define GLL16(gsrc, ldsbase) __builtin_amdgcn_global_load_lds(                    \
    (__attribute__((address_space(1))) void*)(uintptr_t)(gsrc),                   \
    (__attribute__((address_space(3))) void*)(uint32_t)(uintptr_t)(ldsbase),      \
    16, 0, 0)

// ---------------------------------------------------------------------------
// K0a: convert x / w_qkv / w_proj to bf16.
// ---------------------------------------------------------------------------
#define NX4  1572864   // 6291456/4
#define NW14 442368
#define NW24 147456
#define NXW4 (NX4 + NW14 + NW24)   // 2162688

__global__ __launch_bounds__(256) void prep_xw(
    const float4* __restrict__ x, const float4* __restrict__ wq,
    const float4* __restrict__ wp,
    ushort4* __restrict__ xb, ushort4* __restrict__ wqb,
    ushort4* __restrict__ wpb)
{
    size_t i = (size_t)blockIdx.x * 256 + threadIdx.x;
    float4 v; ushort4* dst; size_t j;
    if (i < NX4)            { j = i;               v = x[j];  dst = xb;  }
    else if (i < NX4 + NW14){ j = i - NX4;         v = wq[j]; dst = wqb; }
    else                    { j = i - (NX4 + NW14);v = wp[j]; dst = wpb; }
    ushort4 o; o.x = f2b(v.x); o.y = f2b(v.y); o.z = f2b(v.z); o.w = f2b(v.w);
    dst[j] = o;
}

// ---------------------------------------------------------------------------
// K0b: gate = bf16(GATE_SCALE * sigmoid(mask)), permuted into 16x16 MFMA
// C-fragment order (same layout as R3/R4): tile (h,qt,kt); lane (w,l) slot
// (w*64+l)*16, inner idx=i*4+nt <-> row 16w+4fq+i, col nt*16+fr.
// v2: fully-coalesced float4 reads + LDS-transpose + contiguous 8KB writes.
// ---------------------------------------------------------------------------
__global__ __launch_bounds__(256) void prep_gate(
    const float4* __restrict__ mask4, u16* __restrict__ gp)
{
    __shared__ u16 L[64][72];                   // +8 u16 pad
    const int bid = blockIdx.x;                 // h*256 + qt*16 + kt
    const int kt = bid & 15, qt = (bid >> 4) & 15, h = bid >> 8;
    const int t = threadIdx.x;

    #pragma unroll
    for (int s = 0; s < 4; ++s) {
        const int idx = t + s * 256;            // 0..1023
        const int row = idx >> 4, c4 = idx & 15;
        float4 v = mask4[(size_t)(h * 1024 + qt * 64 + row) * 256 + kt * 16 + c4];
        L[row][c4 * 4 + 0] = f2b(GATE_SCALE / (1.f + __expf(-v.x)));
        L[row][c4 * 4 + 1] = f2b(GATE_SCALE / (1.f + __expf(-v.y)));
        L[row][c4 * 4 + 2] = f2b(GATE_SCALE / (1.f + __expf(-v.z)));
        L[row][c4 * 4 + 3] = f2b(GATE_SCALE / (1.f + __expf(-v.w)));
    }
    __syncthreads();

    const int w = t >> 6, l = t & 63;
    const int fq = l >> 4, fr = l & 15;
    union { u16 u[16]; float4 f[2]; } vals;
    #pragma unroll
    for (int i = 0; i < 4; ++i)
        #pragma unroll
        for (int nt = 0; nt < 4; ++nt)
            vals.u[i * 4 + nt] = L[16 * w + 4 * fq + i][nt * 16 + fr];
    float4* dst = (float4*)(gp + (size_t)bid * 4096 + (size_t)t * 16);
    dst[0] = vals.f[0];
    dst[1] = vals.f[1];
}

// ---------------------------------------------------------------------------
// K1: QKV GEMM, bf16 MFMA 16x16x32, 128x128 tile, BK=32, pipelined dbuf.
// q/k written (B,H,N,64); V written TRANSPOSED (B,H,64,N).
// ---------------------------------------------------------------------------
__global__ __launch_bounds__(256) void qkv_gemm(
    const u16* __restrict__ xb, const u16* __restrict__ wb,
    u16* __restrict__ qb, u16* __restrict__ kb, u16* __restrict__ vb)
{
    __shared__ u16 As[2][4096];
    __shared__ u16 Bs[2][4096];
    const int t = threadIdx.x, l = t & 63, w = t >> 6;
    const int wm = (w & 1) * 64, wn = (w >> 1) * 64;
    const int m0 = blockIdx.y * 128, c0 = blockIdx.x * 128;

    f32x4 acc[4][4];
    #pragma unroll
    for (int i = 0; i < 4; ++i)
        #pragma unroll
        for (int j = 0; j < 4; ++j) { f32x4 z = {0.f,0.f,0.f,0.f}; acc[i][j] = z; }

    const int srow = l >> 2, sseg = l & 3;
    const int gcol = ((sseg ^ (srow & 3)) << 3);
    const u16* a0 = xb + (size_t)(m0 + w * 16 + srow) * 768 + gcol;
    const u16* a1 = a0 + (size_t)64 * 768;
    const u16* b0p = wb + (size_t)(c0 + w * 16 + srow) * 768 + gcol;
    const u16* b1p = b0p + (size_t)64 * 768;
    const int wofs = w * 512;

    const int fr = l & 15, fq = l >> 4;
    const int fseg = (fq ^ (fr & 3)) << 3;

    GLL16(a0, &As[0][wofs]);
    GLL16(a1, &As[0][2048 + wofs]);
    GLL16(b0p, &Bs[0][wofs]);
    GLL16(b1p, &Bs[0][2048 + wofs]);

    for (int kt = 0; kt < 24; ++kt) {
        __syncthreads();
        if (kt < 23) {
            const int kn = (kt + 1) * 32;
            const int nb = (kt + 1) & 1;
            GLL16(a0 + kn, &As[nb][wofs]);
            GLL16(a1 + kn, &As[nb][2048 + wofs]);
            GLL16(b0p + kn, &Bs[nb][wofs]);
            GLL16(b1p + kn, &Bs[nb][2048 + wofs]);
        }
        const u16* A = As[kt & 1];
        const u16* B = Bs[kt & 1];
        short8 af[4], bf[4];
        #pragma unroll
        for (int mt = 0; mt < 4; ++mt)
            af[mt] = *(const short8*)&A[(wm + mt * 16 + fr) * 32 + fseg];
        #pragma unroll
        for (int nt = 0; nt < 4; ++nt)
            bf[nt] = *(const short8*)&B[(wn + nt * 16 + fr) * 32 + fseg];
        #pragma unroll
        for (int mt = 0; mt < 4; ++mt)
            #pragma unroll
            for (int nt = 0; nt < 4; ++nt)
                acc[mt][nt] = __builtin_amdgcn_mfma_f32_16x16x32_bf16(
                    af[mt], bf[nt], acc[mt][nt], 0, 0, 0);
    }

    const int b = m0 >> 10;
    const int n0 = m0 & 1023;
    #pragma unroll
    for (int nt = 0; nt < 4; ++nt) {
        const int c = c0 + wn + nt * 16 + fr;
        const int which = c / 768;
        const int rem = c - which * 768;
        const int h = rem >> 6, d = rem & 63;
        if (which < 2) {
            u16* dst = ((which == 0) ? qb : kb)
                       + ((size_t)(b * 12 + h) * 1024) * 64 + d;
            #pragma unroll
            for (int mt = 0; mt < 4; ++mt)
                #pragma unroll
                for (int r = 0; r < 4; ++r) {
                    const int n = n0 + wm + mt * 16 + fq * 4 + r;
                    dst[(size_t)n * 64] = f2b(acc[mt][nt][r]);
                }
        } else {
            u16* dst = vb + ((size_t)(b * 12 + h) * 64 + d) * 1024
                          + n0 + wm + fq * 4;
            #pragma unroll
            for (int mt = 0; mt < 4; ++mt) {
                ushort4 pk;
                pk.x = f2b(acc[mt][nt][0]); pk.y = f2b(acc[mt][nt][1]);
                pk.z = f2b(acc[mt][nt][2]); pk.w = f2b(acc[mt][nt][3]);
                *(ushort4*)(dst + mt * 16) = pk;
            }
        }
    }
}

// ---------------------------------------------------------------------------
// K2: flash attention, 16x16x32 MFMA (R4-verified fragments/swizzles/gate
// prefetch), TWO 64-row Q-tiles per block: K/V fragments read from LDS once
// and reused in registers for both halves -> ~50% cut of the LDS-read
// bottleneck. Single-buffered K/V (dbuf measured neutral), 40 KB LDS,
// grid 768 = 3 blocks/CU.
// ---------------------------------------------------------------------------
__global__ __launch_bounds__(256, 3) void flash_attn(
    const u16* __restrict__ qb, const u16* __restrict__ kb,
    const u16* __restrict__ vt, const u16* __restrict__ gperm,
    u16* __restrict__ aob)
{
    __shared__ u16 Qs[8192], Ks[4096], Vts[4096], Ps[4096];
    const int t = threadIdx.x, l = t & 63, w = t >> 6;
    const int bid = blockIdx.x;                 // bh*8 + qtb
    const int qtb = bid & 7, bh = bid >> 3;
    const int h = bh % 12, b = bh / 12;
    const int q0 = qtb * 128;

    const u16* hq = qb + (size_t)bh * 65536;
    const u16* hk = kb + (size_t)bh * 65536;
    const u16* hv = vt + (size_t)bh * 65536;
    // gate tiles (h, 2*qtb + qh, kt); qh=1 at +16 tiles = +65536 u16
    const u16* hgb = gperm + ((size_t)h * 256 + qtb * 32) * 4096 + (w * 64 + l) * 16;

    const int sr = l >> 3, ss = l & 7;
    const int sg = ((ss ^ (sr & 7)) << 3);
    const int j0 = w * 2, j1 = j0 + 1;

    // stage Q (128 rows, 16 slices) + kt=0 K/V
    #pragma unroll
    for (int jq = 0; jq < 4; ++jq) {
        const int j = w * 4 + jq;
        GLL16(hq + (size_t)(q0 + j * 8 + sr) * 64 + sg, Qs + j * 512);
    }
    GLL16(hk + (size_t)(j0 * 8 + sr) * 64 + sg, Ks + j0 * 512);
    GLL16(hk + (size_t)(j1 * 8 + sr) * 64 + sg, Ks + j1 * 512);
    GLL16(hv + (size_t)(j0 * 8 + sr) * 1024 + sg, Vts + j0 * 512);
    GLL16(hv + (size_t)(j1 * 8 + sr) * 1024 + sg, Vts + j1 * 512);
    __syncthreads();

    const int fq = l >> 4, fr = l & 15;
    const int sega = ((fq ^ (fr & 7)) << 3);
    const int segb = (((4 + fq) ^ (fr & 7)) << 3);

    // hoisted Q A-frags (kt-invariant), both halves
    short8 aq[2][2];
    #pragma unroll
    for (int qh = 0; qh < 2; ++qh) {
        const int row = 16 * w + fr;
        aq[qh][0] = *(const short8*)&Qs[qh * 4096 + row * 64 + sega];
        aq[qh][1] = *(const short8*)&Qs[qh * 4096 + row * 64 + segb];
    }

    // gate prefetch for kt=0 (both halves)
    short8 gn[4];
    gn[0] = *(const short8*)(hgb);
    gn[1] = *(const short8*)(hgb + 8);
    gn[2] = *(const short8*)(hgb + 65536);
    gn[3] = *(const short8*)(hgb + 65536 + 8);

    float l_part[2][4] = {{0.f,0.f,0.f,0.f},{0.f,0.f,0.f,0.f}};
    f32x4 o[2][4];
    #pragma unroll
    for (int qh = 0; qh < 2; ++qh)
        #pragma unroll
        for (int nt = 0; nt < 4; ++nt) { f32x4 z = {0.f,0.f,0.f,0.f}; o[qh][nt] = z; }

    for (int kt = 0; kt < 16; ++kt) {
        short8 g[4];
        #pragma unroll
        for (int s = 0; s < 4; ++s) g[s] = gn[s];
        if (kt < 15) {                          // register prefetch one iter ahead
            const size_t go = (size_t)(kt + 1) * 4096;
            gn[0] = *(const short8*)(hgb + go);
            gn[1] = *(const short8*)(hgb + go + 8);
            gn[2] = *(const short8*)(hgb + 65536 + go);
            gn[3] = *(const short8*)(hgb + 65536 + go + 8);
        }

        // S = Q . K^T for both halves; k-frags read once, used twice
        f32x4 sv[2][4];
        #pragma unroll
        for (int nt = 0; nt < 4; ++nt) {
            short8 kf0 = *(const short8*)&Ks[(nt * 16 + fr) * 64 + sega];
            short8 kf1 = *(const short8*)&Ks[(nt * 16 + fr) * 64 + segb];
            f32x4 z0 = {0.f,0.f,0.f,0.f};
            z0 = __builtin_amdgcn_mfma_f32_16x16x32_bf16(aq[0][0], kf0, z0, 0, 0, 0);
            z0 = __builtin_amdgcn_mfma_f32_16x16x32_bf16(aq[0][1], kf1, z0, 0, 0, 0);
            sv[0][nt] = z0;
            f32x4 z1 = {0.f,0.f,0.f,0.f};
            z1 = __builtin_amdgcn_mfma_f32_16x16x32_bf16(aq[1][0], kf0, z1, 0, 0, 0);
            z1 = __builtin_amdgcn_mfma_f32_16x16x32_bf16(aq[1][1], kf1, z1, 0, 0, 0);
            sv[1][nt] = z1;
        }

        // gate + exp + P->LDS per half; ap frags captured before Ps reuse
        short8 ap[2][2];
        #pragma unroll
        for (int qh = 0; qh < 2; ++qh) {
            #pragma unroll
            for (int i = 0; i < 4; ++i) {
                const int pr = 4 * fq + i;
                #pragma unroll
                for (int nt = 0; nt < 4; ++nt) {
                    const int idx = i * 4 + nt;
                    const float gv = b2f((u16)(idx < 8 ? g[2 * qh][idx]
                                                       : g[2 * qh + 1][idx - 8]));
                    const float p = FEXP2(sv[qh][nt][i] * gv);
                    l_part[qh][i] += p;
                    const int col = nt * 16 + fr;
                    Ps[w * 1024 + pr * 64 + (((col >> 3) ^ (pr & 7)) << 3) + (col & 7)]
                        = f2b_hu(p);
                }
            }
            ap[qh][0] = *(const short8*)&Ps[w * 1024 + fr * 64 + sega];
            ap[qh][1] = *(const short8*)&Ps[w * 1024 + fr * 64 + segb];
        }

        // O += P . V for both halves; v-frags read once, used twice
        #pragma unroll
        for (int nt = 0; nt < 4; ++nt) {
            short8 vf0 = *(const short8*)&Vts[(nt * 16 + fr) * 64 + sega];
            short8 vf1 = *(const short8*)&Vts[(nt * 16 + fr) * 64 + segb];
            o[0][nt] = __builtin_amdgcn_mfma_f32_16x16x32_bf16(ap[0][0], vf0, o[0][nt], 0, 0, 0);
            o[0][nt] = __builtin_amdgcn_mfma_f32_16x16x32_bf16(ap[0][1], vf1, o[0][nt], 0, 0, 0);
            o[1][nt] = __builtin_amdgcn_mfma_f32_16x16x32_bf16(ap[1][0], vf0, o[1][nt], 0, 0, 0);
            o[1][nt] = __builtin_amdgcn_mfma_f32_16x16x32_bf16(ap[1][1], vf1, o[1][nt], 0, 0, 0);
        }

        // stage next K/V chunk
        if (kt < 15) {
            __syncthreads();
            const size_t ko = (size_t)(kt + 1) * 64;
            GLL16(hk + (ko + j0 * 8 + sr) * 64 + sg, Ks + j0 * 512);
            GLL16(hk + (ko + j1 * 8 + sr) * 64 + sg, Ks + j1 * 512);
            GLL16(hv + (size_t)(j0 * 8 + sr) * 1024 + ko + sg, Vts + j0 * 512);
            GLL16(hv + (size_t)(j1 * 8 + sr) * 1024 + ko + sg, Vts + j1 * 512);
            __syncthreads();
        }
    }

    // deferred l reduction + epilogue per half
    #pragma unroll
    for (int qh = 0; qh < 2; ++qh) {
        #pragma unroll
        for (int i = 0; i < 4; ++i) {
            float s = l_part[qh][i];
            s += __shfl_xor(s, 1, 16);
            s += __shfl_xor(s, 2, 16);
            s += __shfl_xor(s, 4, 16);
            s += __shfl_xor(s, 8, 16);
            const float inv = 1.f / s;
            const int n = q0 + qh * 64 + 16 * w + 4 * fq + i;
            const size_t rowoff = ((size_t)b * 1024 + n) * 768 + h * 64;
            #pragma unroll
            for (int nt = 0; nt < 4; ++nt)
                aob[rowoff + nt * 16 + fr] = f2b(o[qh][nt][i] * inv);
        }
    }
}

// ---------------------------------------------------------------------------
// K3: output projection, bf16 MFMA, pipelined, fp32 out + bias.
// ---------------------------------------------------------------------------
__global__ __launch_bounds__(256) void proj_gemm(
    const u16* __restrict__ aob, const u16* __restrict__ wb,
    const float* __restrict__ bproj, float* __restrict__ out)
{
    __shared__ u16 As[2][4096];
    __shared__ u16 Bs[2][4096];
    const int t = threadIdx.x, l = t & 63, w = t >> 6;
    const int wm = (w & 1) * 64, wn = (w >> 1) * 64;
    const int m0 = blockIdx.y * 128, c0 = blockIdx.x * 128;

    f32x4 acc[4][4];
    #pragma unroll
    for (int i = 0; i < 4; ++i)
        #pragma unroll
        for (int j = 0; j < 4; ++j) { f32x4 z = {0.f,0.f,0.f,0.f}; acc[i][j] = z; }

    const int srow = l >> 2, sseg = l & 3;
    const int gcol = ((sseg ^ (srow & 3)) << 3);
    const u16* a0 = aob + (size_t)(m0 + w * 16 + srow) * 768 + gcol;
    const u16* a1 = a0 + (size_t)64 * 768;
    const u16* b0p = wb + (size_t)(c0 + w * 16 + srow) * 768 + gcol;
    const u16* b1p = b0p + (size_t)64 * 768;
    const int wofs = w * 512;

    const int fr = l & 15, fq = l >> 4;
    const int fseg = (fq ^ (fr & 3)) << 3;

    GLL16(a0, &As[0][wofs]);
    GLL16(a1, &As[0][2048 + wofs]);
    GLL16(b0p, &Bs[0][wofs]);
    GLL16(b1p, &Bs[0][2048 + wofs]);

    for (int kt = 0; kt < 24; ++kt) {
        __syncthreads();
        if (kt < 23) {
            const int kn = (kt + 1) * 32;
            const int nb = (kt + 1) & 1;
            GLL16(a0 + kn, &As[nb][wofs]);
            GLL16(a1 + kn, &As[nb][2048 + wofs]);
            GLL16(b0p + kn, &Bs[nb][wofs]);
            GLL16(b1p + kn, &Bs[nb][2048 + wofs]);
        }
        const u16* A = As[kt & 1];
        const u16* B = Bs[kt & 1];
        short8 af[4], bf[4];
        #pragma unroll
        for (int mt = 0; mt < 4; ++mt)
            af[mt] = *(const short8*)&A[(wm + mt * 16 + fr) * 32 + fseg];
        #pragma unroll
        for (int nt = 0; nt < 4; ++nt)
            bf[nt] = *(const short8*)&B[(wn + nt * 16 + fr) * 32 + fseg];
        #pragma unroll
        for (int mt = 0; mt < 4; ++mt)
            #pragma unroll
            for (int nt = 0; nt < 4; ++nt)
                acc[mt][nt] = __builtin_amdgcn_mfma_f32_16x16x32_bf16(
                    af[mt], bf[nt], acc[mt][nt], 0, 0, 0);
    }

    #pragma unroll
    for (int nt = 0; nt < 4; ++nt) {
        const int c = c0 + wn + nt * 16 + fr;
        const float bias = bproj[c];
        #pragma unroll
        for (int mt = 0; mt < 4; ++mt)
            #pragma unroll
            for (int r = 0; r < 4; ++r) {
                const int m = m0 + wm + mt * 16 + fq * 4 + r;
                out[(size_t)m * 768 + c] = acc[mt][nt][r] + bias;
            }
    }
}

// ---------------------------------------------------------------------------
extern "C" void kernel_launch(void* const* d_in, const int* in_sizes, int n_in,
                              void* d_out, int out_size, void* d_ws, size_t ws_size,
                              hipStream_t stream)
{
    const float* x     = (const float*)d_in[0];
    const float* wqkv  = (const float*)d_in[1];
    const float* wproj = (const float*)d_in[2];
    const float* bproj = (const float*)d_in[3];
    const float* mask  = (const float*)d_in[4];
    float* out = (float*)d_out;

    char* ws = (char*)d_ws;
    u16* gperm  = (u16*)(ws);               // 25,165,824 B
    u16* xb     = (u16*)(ws + 25165824);    // 12,582,912 B
    u16* wqkvb  = (u16*)(ws + 37748736);    //  3,538,944 B
    u16* wprojb = (u16*)(ws + 41287680);    //  1,179,648 B
    u16* qb     = (u16*)(ws + 42467328);    // 12,582,912 B
    u16* kb     = (u16*)(ws + 55050240);    // 12,582,912 B
    u16* vb     = (u16*)(ws + 67633152);    // 12,582,912 B (transposed: B,H,64,N)
    u16* aob    = (u16*)(ws + 80216064);    // 12,582,912 B  (total 92.8 MB)

    prep_xw<<<NXW4 / 256, 256, 0, stream>>>(
        (const float4*)x, (const float4*)wqkv, (const float4*)wproj,
        (ushort4*)xb, (ushort4*)wqkvb, (ushort4*)wprojb);

    prep_gate<<<3072, 256, 0, stream>>>((const float4*)mask, gperm);

    qkv_gemm<<<dim3(18, 64), 256, 0, stream>>>(xb, wqkvb, qb, kb, vb);

    flash_attn<<<768, 256, 0, stream>>>(qb, kb, vb, gperm, aob);

    proj_gemm<<<dim3(6, 64), 256, 0, stream>>>(aob, wprojb, bproj, out);
}